// Round 13
// baseline (75.311 us; speedup 1.0000x reference)
//
#include <hip/hip_runtime.h>
#include <hip/hip_bf16.h>

#define B_ 64
#define S_ 128
#define D_ 1024
#define O_ 1024
#define L_ 16

typedef __bf16 bf16x8 __attribute__((ext_vector_type(8)));
typedef float f32x4 __attribute__((ext_vector_type(4)));
typedef unsigned u32x4 __attribute__((ext_vector_type(4)));

// ws layout (bytes):
//  [0, 33554432)        W' = bf16(w), row-major [16][1024][1024]
//  [33554432, 50331648) X'' = bf16(x), A-FRAGMENT-MAJOR:
//                       per s (131072 B): [frag: (kt*2+kk)*4+mi][lane]*16B
//                       piece(b,s,d8) at s*131072 + ((kt*2+kk)*4+mi)*1024
//                         + ((b&15) + (d8&3)*16)*16,  kt=d8>>3, kk=(d8>>2)&1, mi=b>>4
//  [50331648]           npairs (int, 16-byte slot)
//  [50331664, +72*16)   pairs int4 {s0, s1, layer, 0}
#define WS_W     0ull
#define WS_X     33554432ull
#define WS_P     50331648ull
#define WS_PAIRS (WS_P + 16ull)
#define WS_NEED  (WS_PAIRS + 72ull * 16ull)

__device__ __forceinline__ unsigned f2bf2(float a, float b) {
    union { float f; unsigned u; } x{a}, y{b};
    unsigned lo = x.u + 0x7FFFu + ((x.u >> 16) & 1u);
    unsigned hi = y.u + 0x7FFFu + ((y.u >> 16) & 1u);
    return (lo >> 16) | (hi & 0xFFFF0000u);
}

__device__ __forceinline__ void gload16(const void* g, void* l) {
    __builtin_amdgcn_global_load_lds(
        (const __attribute__((address_space(1))) void*)g,
        (__attribute__((address_space(3))) void*)l, 16, 0, 0);
}

// ---- pass 1: fp32 -> bf16. W: linear row-major (R11). x: fragment-major
// permutation — reads stay coalesced (8 consecutive floats/thread); 16 B
// scattered writes merge in L2 (write-back) so HBM sees each line once.
// Block 0 lanes 0-15 build the layer-grouped s-pairs.
__global__ __launch_bounds__(256) void moshi_convert(
    const float* __restrict__ x, const float* __restrict__ w,
    const int* __restrict__ lidx, unsigned char* __restrict__ ws) {
    if (blockIdx.x == 0 && threadIdx.x < 16) {
        int t = threadIdx.x;
        int cnt[16];
        #pragma unroll 1
        for (int m = 0; m < 16; ++m) cnt[m] = 0;
        for (int s = 0; s < S_; ++s) ++cnt[lidx[s]];
        int off = 0;
        for (int m = 0; m < t; ++m) off += (cnt[m] + 1) >> 1;
        int4* pairs = (int4*)(ws + WS_PAIRS);
        int k = 0, prev = -1;
        for (int s = 0; s < S_; ++s) {
            if (lidx[s] == t) {
                if (k & 1) pairs[off + (k >> 1)] = make_int4(prev, s, t, 0);
                prev = s; ++k;
            }
        }
        if (k & 1) pairs[off + (k >> 1)] = make_int4(prev, prev, t, 0);
        if (t == 0) {
            int tot = 0;
            for (int m = 0; m < 16; ++m) tot += (cnt[m] + 1) >> 1;
            *(int*)(ws + WS_P) = tot;
        }
    }
    if (blockIdx.x < 8192) {                    // W: 4194304 float4s, linear
        unsigned i0 = blockIdx.x * 512u + threadIdx.x;
        const float4* src = reinterpret_cast<const float4*>(w);
        uint2* dst = reinterpret_cast<uint2*>(ws + WS_W);
        float4 v0 = src[i0];
        float4 v1 = src[i0 + 256];
        dst[i0]       = make_uint2(f2bf2(v0.x, v0.y), f2bf2(v0.z, v0.w));
        dst[i0 + 256] = make_uint2(f2bf2(v1.x, v1.y), f2bf2(v1.z, v1.w));
    } else {                                    // x: 1048576 pieces of 8 floats
        unsigned p = (blockIdx.x - 8192u) * 256u + threadIdx.x;
        const float4* src = reinterpret_cast<const float4*>(x);
        float4 v0 = src[2u * p];
        float4 v1 = src[2u * p + 1u];
        unsigned b = p >> 14, s = (p >> 7) & 127u, d8 = p & 127u;
        unsigned kt = d8 >> 3, kk = (d8 >> 2) & 1u, lh = d8 & 3u;
        unsigned mi = b >> 4, ml = b & 15u;
        unsigned dstb = s * 131072u + (((kt * 2u + kk) * 4u + mi) << 10)
                      + ((ml + lh * 16u) << 4);
        u32x4 pk = { f2bf2(v0.x, v0.y), f2bf2(v0.z, v0.w),
                     f2bf2(v1.x, v1.y), f2bf2(v1.z, v1.w) };
        *reinterpret_cast<u32x4*>(ws + WS_X + dstb) = pk;
    }
}

// ---- pass 2: paired GEMM, x-direct. Tile M=128 (2s x 64b) x N=128, BK=64,
// 8 waves (2 wm x 4 wn), 64x32 per wave. W staged via gload_lds (source-side
// XOR swizzle, R11); A-fragments loaded DIRECTLY global->VGPR from the
// fragment-major X'' (1 KB coalesced per load) — x never touches LDS, so
// gload_lds staged bytes halve (crit-CU 1.5 MB -> 768 KB).
__global__ __launch_bounds__(512, 4) void moshi_gemm_xd(
    const unsigned char* __restrict__ ws, float* __restrict__ out) {
    __shared__ __align__(16) unsigned char lw[16384];   // 128(o) x 64(k) bf16, swizzled

    // bijective XCD-chunk swizzle: grid 576 = 8 chunks of 72 (9 pairs x 8 nt)
    const int bid = (blockIdx.x & 7) * 72 + (blockIdx.x >> 3);
    const int pi = bid >> 3;
    const int nt = bid & 7;
    const int np = *reinterpret_cast<const int*>(ws + WS_P);
    if (pi >= np) return;   // block-uniform exit before any barrier
    const int4 pr = *reinterpret_cast<const int4*>(ws + WS_PAIRS + 16ull * pi);
    const int s0 = pr.x, s1 = pr.y, l = pr.z;

    const int tid = threadIdx.x, lane = tid & 63, wid = tid >> 6;
    const int rowq = tid >> 3;                 // 0..63
    const int c16  = (tid & 7) << 4;
    const int csw  = c16 ^ ((rowq & 7) << 4);  // source-side swizzle (W)
    const unsigned char* wsrc0 = ws + WS_W
        + ((size_t)(l * 1024 + nt * 128 + rowq) << 11) + csw;
    const unsigned char* wsrc1 = wsrc0 + ((size_t)64 << 11);

    const int wm = wid >> 2, wn = wid & 3;
    const int swz = (lane & 7) << 4;
    const int kb  = (lane >> 4) << 4;
    const int b_base = (wn * 32 + (lane & 15)) * 128 + kb;   // W rows (LDS)
    const int s_sel = wm ? s1 : s0;
    const unsigned char* xA = ws + WS_X + (size_t)s_sel * 131072 + lane * 16;

    f32x4 acc[4][2];
    #pragma unroll
    for (int i = 0; i < 4; ++i)
        #pragma unroll
        for (int j = 0; j < 2; ++j) acc[i][j] = (f32x4)0.0f;

    #pragma unroll 1
    for (int kt = 0; kt < 16; ++kt) {
        __syncthreads();                       // prior LDS reads done
        gload16(wsrc0 + kt * 128, lw + tid * 16);
        gload16(wsrc1 + kt * 128, lw + tid * 16 + 8192);
        // A-fragments direct from global (overlap the gload_lds drain)
        bf16x8 af[2][4];
        #pragma unroll
        for (int kk = 0; kk < 2; ++kk)
            #pragma unroll
            for (int mi = 0; mi < 4; ++mi)
                af[kk][mi] = *reinterpret_cast<const bf16x8*>(
                    xA + (((kt * 2 + kk) * 4 + mi) << 10));
        __syncthreads();                       // W tile visible
        #pragma unroll
        for (int kk = 0; kk < 2; ++kk) {
            bf16x8 bfr[2];
            #pragma unroll
            for (int ni = 0; ni < 2; ++ni)
                bfr[ni] = *reinterpret_cast<const bf16x8*>(
                    lw + (((b_base + kk * 64) ^ swz) + ni * 2048));
            #pragma unroll
            for (int mi = 0; mi < 4; ++mi)
                #pragma unroll
                for (int ni = 0; ni < 2; ++ni)
                    acc[mi][ni] = __builtin_amdgcn_mfma_f32_16x16x32_bf16(
                        af[kk][mi], bfr[ni], acc[mi][ni], 0, 0, 0);
        }
    }

    // epilogue: C/D col = lane&15 (o), row = (lane>>4)*4 + reg (b)
    const int col0 = nt * 128 + wn * 32 + (lane & 15);
    const int r0 = (lane >> 4) << 2;
    #pragma unroll
    for (int mi = 0; mi < 4; ++mi)
        #pragma unroll
        for (int ni = 0; ni < 2; ++ni)
            #pragma unroll
            for (int r = 0; r < 4; ++r) {
                int b = mi * 16 + r0 + r;
                out[((size_t)b * S_ + s_sel) * O_ + col0 + ni * 16] = acc[mi][ni][r];
            }
}

// ---- fallback (round-1 kernel) if ws is too small ----
__global__ __launch_bounds__(256) void moshi_flin_fallback(
    const float* __restrict__ x, const int* __restrict__ lidx,
    const float* __restrict__ w, float* __restrict__ out) {
    __shared__ __align__(16) unsigned char lxs[64 * 128];
    __shared__ __align__(16) unsigned char lws[128 * 128];
    const int bid = blockIdx.x;
    const int s = bid >> 3, n0 = (bid & 7) << 7;
    const int tid = threadIdx.x, lane = tid & 63, wid = tid >> 6;
    const int idx = lidx[s];
    const float* wb = w + (size_t)idx * O_ * D_ + (size_t)n0 * D_;
    const float* xb = x + (size_t)s * D_;
    const int swz = (lane & 7) << 4;
    const int kb = (lane >> 4) << 4;
    const int a_base = (lane & 15) * 128 + kb;
    const int b_base = (wid * 32 + (lane & 15)) * 128 + kb;
    f32x4 acc[4][2];
    #pragma unroll
    for (int i = 0; i < 4; ++i)
        #pragma unroll
        for (int j = 0; j < 2; ++j) acc[i][j] = (f32x4)0.0f;
    for (int kt = 0; kt < D_; kt += 64) {
        __syncthreads();
        #pragma unroll
        for (int p = 0; p < 4; ++p) {
            int f = tid + p * 256, row = f >> 4, cc = (f & 15) << 2;
            const float4 v = *reinterpret_cast<const float4*>(
                xb + (size_t)row * (S_ * D_) + kt + cc);
            uint2 pk = { f2bf2(v.x, v.y), f2bf2(v.z, v.w) };
            *reinterpret_cast<uint2*>(&lxs[(row * 128 + cc * 2) ^ ((row & 7) << 4)]) = pk;
        }
        #pragma unroll
        for (int p = 0; p < 8; ++p) {
            int f = tid + p * 256, row = f >> 4, cc = (f & 15) << 2;
            const float4 v = *reinterpret_cast<const float4*>(
                wb + (size_t)row * D_ + kt + cc);
            uint2 pk = { f2bf2(v.x, v.y), f2bf2(v.z, v.w) };
            *reinterpret_cast<uint2*>(&lws[(row * 128 + cc * 2) ^ ((row & 7) << 4)]) = pk;
        }
        __syncthreads();
        #pragma unroll
        for (int kk = 0; kk < 2; ++kk) {
            bf16x8 af[4], bfr[2];
            #pragma unroll
            for (int mi = 0; mi < 4; ++mi)
                af[mi] = *reinterpret_cast<const bf16x8*>(
                    &lxs[(((a_base + kk * 64) ^ swz) + mi * 2048)]);
            #pragma unroll
            for (int ni = 0; ni < 2; ++ni)
                bfr[ni] = *reinterpret_cast<const bf16x8*>(
                    &lws[(((b_base + kk * 64) ^ swz) + ni * 2048)]);
            #pragma unroll
            for (int mi = 0; mi < 4; ++mi)
                #pragma unroll
                for (int ni = 0; ni < 2; ++ni)
                    acc[mi][ni] = __builtin_amdgcn_mfma_f32_16x16x32_bf16(
                        af[mi], bfr[ni], acc[mi][ni], 0, 0, 0);
        }
    }
    float* ob = out + (size_t)s * O_ + n0 + wid * 32 + (lane & 15);
    const int r0 = (lane >> 4) << 2;
    #pragma unroll
    for (int mi = 0; mi < 4; ++mi)
        #pragma unroll
        for (int ni = 0; ni < 2; ++ni)
            #pragma unroll
            for (int r = 0; r < 4; ++r) {
                int b = mi * 16 + r0 + r;
                ob[(size_t)b * (S_ * O_) + ni * 16] = acc[mi][ni][r];
            }
}

extern "C" void kernel_launch(void* const* d_in, const int* in_sizes, int n_in,
                              void* d_out, int out_size, void* d_ws, size_t ws_size,
                              hipStream_t stream) {
    const float* x  = (const float*)d_in[0];
    const int* lidx = (const int*)d_in[1];
    const float* w  = (const float*)d_in[2];
    float* out      = (float*)d_out;

    if (ws_size < WS_NEED) {
        moshi_flin_fallback<<<dim3(128 * 8), dim3(256), 0, stream>>>(x, lidx, w, out);
        return;
    }
    unsigned char* ws = (unsigned char*)d_ws;
    // W: 8192 blocks linear; x: 4096 blocks fragment-major permutation
    moshi_convert<<<dim3(12288), dim3(256), 0, stream>>>(x, w, lidx, ws);
    // static 576-grid (R11 mapping — R12's queue reverted)
    moshi_gemm_xd<<<dim3(72 * 8), dim3(512), 0, stream>>>(ws, out);
}

// Round 14
// 56.447 us; speedup vs baseline: 1.3342x; 1.3342x over previous
//
#include <hip/hip_runtime.h>
#include <hip/hip_bf16.h>

#define B_ 64
#define S_ 128
#define D_ 1024
#define O_ 1024
#define L_ 16

typedef __bf16 bf16x8 __attribute__((ext_vector_type(8)));
typedef float f32x4 __attribute__((ext_vector_type(4)));

// ws layout (bytes):
//  [0, 33554432)        W' = bf16(w), row-major [16][1024][1024]
//  [33554432, 50331648) X' = bf16(x), S-MAJOR [s:128][b:64][d:1024]
//  [50331648]           npairs (int, 16-byte slot)
//  [50331664, +72*16)   pairs int4 {s0, s1, layer, 0}
#define WS_W     0ull
#define WS_X     33554432ull
#define WS_P     50331648ull
#define WS_PAIRS (WS_P + 16ull)
#define WS_NEED  (WS_PAIRS + 72ull * 16ull)

__device__ __forceinline__ unsigned f2bf2(float a, float b) {
    union { float f; unsigned u; } x{a}, y{b};
    unsigned lo = x.u + 0x7FFFu + ((x.u >> 16) & 1u);
    unsigned hi = y.u + 0x7FFFu + ((y.u >> 16) & 1u);
    return (lo >> 16) | (hi & 0xFFFF0000u);
}

__device__ __forceinline__ void gload16(const void* g, void* l) {
    __builtin_amdgcn_global_load_lds(
        (const __attribute__((address_space(1))) void*)g,
        (__attribute__((address_space(3))) void*)l, 16, 0, 0);
}

// ---- pass 1: linear fp32 -> bf16 cast. W row-major; x transposed to [s][b][d]
// (reads fully coalesced; x writes are 2 KB-contiguous chunks -> L2 merges).
// Block 0 lanes 0-15 build the layer-grouped s-pairs.
__global__ __launch_bounds__(256) void moshi_convert(
    const float* __restrict__ x, const float* __restrict__ w,
    const int* __restrict__ lidx, unsigned char* __restrict__ ws) {
    if (blockIdx.x == 0 && threadIdx.x < 16) {
        int t = threadIdx.x;
        int cnt[16];
        #pragma unroll 1
        for (int m = 0; m < 16; ++m) cnt[m] = 0;
        for (int s = 0; s < S_; ++s) ++cnt[lidx[s]];
        int off = 0;
        for (int m = 0; m < t; ++m) off += (cnt[m] + 1) >> 1;
        int4* pairs = (int4*)(ws + WS_PAIRS);
        int k = 0, prev = -1;
        for (int s = 0; s < S_; ++s) {
            if (lidx[s] == t) {
                if (k & 1) pairs[off + (k >> 1)] = make_int4(prev, s, t, 0);
                prev = s; ++k;
            }
        }
        if (k & 1) pairs[off + (k >> 1)] = make_int4(prev, prev, t, 0);
        if (t == 0) {
            int tot = 0;
            for (int m = 0; m < 16; ++m) tot += (cnt[m] + 1) >> 1;
            *(int*)(ws + WS_P) = tot;
        }
    }
    unsigned i0 = blockIdx.x * 512u + threadIdx.x;
    if (blockIdx.x < 8192) {                    // W: 4194304 float4s, linear
        const float4* src = reinterpret_cast<const float4*>(w);
        uint2* dst = reinterpret_cast<uint2*>(ws + WS_W);
        float4 v0 = src[i0];
        float4 v1 = src[i0 + 256];
        dst[i0]       = make_uint2(f2bf2(v0.x, v0.y), f2bf2(v0.z, v0.w));
        dst[i0 + 256] = make_uint2(f2bf2(v1.x, v1.y), f2bf2(v1.z, v1.w));
    } else {                                    // x: 2097152 float4s, b<->s transpose
        const float4* src = reinterpret_cast<const float4*>(x);
        uint2* dst = reinterpret_cast<uint2*>(ws + WS_X);
        unsigned j = i0 - 4194304u;
        float4 v0 = src[j];
        float4 v1 = src[j + 256];
        unsigned b0 = j >> 15, s0 = (j >> 8) & 127u, d40 = j & 255u;
        dst[(s0 * 64u + b0) * 256u + d40] =
            make_uint2(f2bf2(v0.x, v0.y), f2bf2(v0.z, v0.w));
        unsigned j1 = j + 256u;
        unsigned b1 = j1 >> 15, s1 = (j1 >> 8) & 127u, d41 = j1 & 255u;
        dst[(s1 * 64u + b1) * 256u + d41] =
            make_uint2(f2bf2(v1.x, v1.y), f2bf2(v1.z, v1.w));
    }
}

// ---- pass 2: paired GEMM (R11 structure, proven 56.3 total). Tile M=128
// (2s x 64b) x N=128, BK=64, 8 waves (2 wm x 4 wn), 64x32 per wave.
// gload_lds with source-side XOR swizzle (m173); static 576-grid with
// bijective XCD-chunk swizzle; 2-barrier K-loop. x' is s-major so each
// pair's staging sources are two contiguous 128 KB blocks.
__global__ __launch_bounds__(512, 4) void moshi_gemm_n128(
    const unsigned char* __restrict__ ws, float* __restrict__ out) {
    __shared__ __align__(16) unsigned char lw[16384];   // 128(o) x 64(k) bf16, swizzled
    __shared__ __align__(16) unsigned char lx[16384];   // s0 rows 0-63 | s1 rows 64-127

    // bijective XCD-chunk swizzle: grid 576 = 8 chunks of 72 (9 pairs x 8 nt)
    const int bid = (blockIdx.x & 7) * 72 + (blockIdx.x >> 3);
    const int pi = bid >> 3;
    const int nt = bid & 7;
    const int np = *reinterpret_cast<const int*>(ws + WS_P);
    if (pi >= np) return;   // block-uniform exit before any barrier
    const int4 pr = *reinterpret_cast<const int4*>(ws + WS_PAIRS + 16ull * pi);
    const int s0 = pr.x, s1 = pr.y, l = pr.z;

    const int tid = threadIdx.x, lane = tid & 63, wid = tid >> 6;

    // staging sources: thread covers LDS byte tid*16 (row = tid/8,
    // col16 = (tid&7)*16); swizzle folded into the global source address.
    const int rowq = tid >> 3;                 // 0..63
    const int c16  = (tid & 7) << 4;
    const int csw  = c16 ^ ((rowq & 7) << 4);
    const unsigned char* wsrc0 = ws + WS_W
        + ((size_t)(l * 1024 + nt * 128 + rowq) << 11) + csw;
    const unsigned char* wsrc1 = wsrc0 + ((size_t)64 << 11);
    const unsigned char* xsrc0 = ws + WS_X + ((size_t)(s0 * 64 + rowq) << 11) + csw;
    const unsigned char* xsrc1 = ws + WS_X + ((size_t)(s1 * 64 + rowq) << 11) + csw;

    // fragment read addressing (proven mapping, LDS-side XOR swizzle)
    const int wm = wid >> 2, wn = wid & 3;
    const int swz = (lane & 7) << 4;
    const int kb  = (lane >> 4) << 4;
    const int a_base = (wm * 64 + (lane & 15)) * 128 + kb;   // x rows
    const int b_base = (wn * 32 + (lane & 15)) * 128 + kb;   // W rows

    f32x4 acc[4][2];
    #pragma unroll
    for (int i = 0; i < 4; ++i)
        #pragma unroll
        for (int j = 0; j < 2; ++j) acc[i][j] = (f32x4)0.0f;

    #pragma unroll 1
    for (int kt = 0; kt < 16; ++kt) {
        __syncthreads();                       // prior LDS reads done
        gload16(wsrc0 + kt * 128, lw + tid * 16);
        gload16(wsrc1 + kt * 128, lw + tid * 16 + 8192);
        gload16(xsrc0 + kt * 128, lx + tid * 16);
        gload16(xsrc1 + kt * 128, lx + tid * 16 + 8192);
        __syncthreads();                       // stage visible
        #pragma unroll
        for (int kk = 0; kk < 2; ++kk) {
            bf16x8 af[4], bfr[2];
            #pragma unroll
            for (int mi = 0; mi < 4; ++mi)
                af[mi] = *reinterpret_cast<const bf16x8*>(
                    lx + (((a_base + kk * 64) ^ swz) + mi * 2048));
            #pragma unroll
            for (int ni = 0; ni < 2; ++ni)
                bfr[ni] = *reinterpret_cast<const bf16x8*>(
                    lw + (((b_base + kk * 64) ^ swz) + ni * 2048));
            #pragma unroll
            for (int mi = 0; mi < 4; ++mi)
                #pragma unroll
                for (int ni = 0; ni < 2; ++ni)
                    acc[mi][ni] = __builtin_amdgcn_mfma_f32_16x16x32_bf16(
                        af[mi], bfr[ni], acc[mi][ni], 0, 0, 0);
        }
    }

    // epilogue: C/D col = lane&15 (o), row = (lane>>4)*4 + reg (b)
    const int s_sel = wm ? s1 : s0;
    const int col0 = nt * 128 + wn * 32 + (lane & 15);
    const int r0 = (lane >> 4) << 2;
    #pragma unroll
    for (int mi = 0; mi < 4; ++mi)
        #pragma unroll
        for (int ni = 0; ni < 2; ++ni)
            #pragma unroll
            for (int r = 0; r < 4; ++r) {
                int b = mi * 16 + r0 + r;
                out[((size_t)b * S_ + s_sel) * O_ + col0 + ni * 16] = acc[mi][ni][r];
            }
}

// ---- fallback (round-1 kernel) if ws is too small ----
__global__ __launch_bounds__(256) void moshi_flin_fallback(
    const float* __restrict__ x, const int* __restrict__ lidx,
    const float* __restrict__ w, float* __restrict__ out) {
    __shared__ __align__(16) unsigned char lxs[64 * 128];
    __shared__ __align__(16) unsigned char lws[128 * 128];
    const int bid = blockIdx.x;
    const int s = bid >> 3, n0 = (bid & 7) << 7;
    const int tid = threadIdx.x, lane = tid & 63, wid = tid >> 6;
    const int idx = lidx[s];
    const float* wb = w + (size_t)idx * O_ * D_ + (size_t)n0 * D_;
    const float* xb = x + (size_t)s * D_;
    const int swz = (lane & 7) << 4;
    const int kb = (lane >> 4) << 4;
    const int a_base = (lane & 15) * 128 + kb;
    const int b_base = (wid * 32 + (lane & 15)) * 128 + kb;
    f32x4 acc[4][2];
    #pragma unroll
    for (int i = 0; i < 4; ++i)
        #pragma unroll
        for (int j = 0; j < 2; ++j) acc[i][j] = (f32x4)0.0f;
    for (int kt = 0; kt < D_; kt += 64) {
        __syncthreads();
        #pragma unroll
        for (int p = 0; p < 4; ++p) {
            int f = tid + p * 256, row = f >> 4, cc = (f & 15) << 2;
            const float4 v = *reinterpret_cast<const float4*>(
                xb + (size_t)row * (S_ * D_) + kt + cc);
            uint2 pk = { f2bf2(v.x, v.y), f2bf2(v.z, v.w) };
            *reinterpret_cast<uint2*>(&lxs[(row * 128 + cc * 2) ^ ((row & 7) << 4)]) = pk;
        }
        #pragma unroll
        for (int p = 0; p < 8; ++p) {
            int f = tid + p * 256, row = f >> 4, cc = (f & 15) << 2;
            const float4 v = *reinterpret_cast<const float4*>(
                wb + (size_t)row * D_ + kt + cc);
            uint2 pk = { f2bf2(v.x, v.y), f2bf2(v.z, v.w) };
            *reinterpret_cast<uint2*>(&lws[(row * 128 + cc * 2) ^ ((row & 7) << 4)]) = pk;
        }
        __syncthreads();
        #pragma unroll
        for (int kk = 0; kk < 2; ++kk) {
            bf16x8 af[4], bfr[2];
            #pragma unroll
            for (int mi = 0; mi < 4; ++mi)
                af[mi] = *reinterpret_cast<const bf16x8*>(
                    &lxs[(((a_base + kk * 64) ^ swz) + mi * 2048)]);
            #pragma unroll
            for (int ni = 0; ni < 2; ++ni)
                bfr[ni] = *reinterpret_cast<const bf16x8*>(
                    &lws[(((b_base + kk * 64) ^ swz) + ni * 2048)]);
            #pragma unroll
            for (int mi = 0; mi < 4; ++mi)
                #pragma unroll
                for (int ni = 0; ni < 2; ++ni)
                    acc[mi][ni] = __builtin_amdgcn_mfma_f32_16x16x32_bf16(
                        af[mi], bfr[ni], acc[mi][ni], 0, 0, 0);
        }
    }
    float* ob = out + (size_t)s * O_ + n0 + wid * 32 + (lane & 15);
    const int r0 = (lane >> 4) << 2;
    #pragma unroll
    for (int mi = 0; mi < 4; ++mi)
        #pragma unroll
        for (int ni = 0; ni < 2; ++ni)
            #pragma unroll
            for (int r = 0; r < 4; ++r) {
                int b = mi * 16 + r0 + r;
                ob[(size_t)b * (S_ * O_) + ni * 16] = acc[mi][ni][r];
            }
}

extern "C" void kernel_launch(void* const* d_in, const int* in_sizes, int n_in,
                              void* d_out, int out_size, void* d_ws, size_t ws_size,
                              hipStream_t stream) {
    const float* x  = (const float*)d_in[0];
    const int* lidx = (const int*)d_in[1];
    const float* w  = (const float*)d_in[2];
    float* out      = (float*)d_out;

    if (ws_size < WS_NEED) {
        moshi_flin_fallback<<<dim3(128 * 8), dim3(256), 0, stream>>>(x, lidx, w, out);
        return;
    }
    unsigned char* ws = (unsigned char*)d_ws;
    // 6291456 float4s total, 512 per block -> 12288 blocks (W: first 8192)
    moshi_convert<<<dim3(12288), dim3(256), 0, stream>>>(x, w, lidx, ws);
    // 72 pair slots x 8 n-tiles, 512 threads
    moshi_gemm_n128<<<dim3(72 * 8), dim3(512), 0, stream>>>(ws, out);
}

// Round 15
// 55.264 us; speedup vs baseline: 1.3627x; 1.0214x over previous
//
#include <hip/hip_runtime.h>
#include <hip/hip_bf16.h>

#define B_ 64
#define S_ 128
#define D_ 1024
#define O_ 1024
#define L_ 16

typedef __bf16 bf16x8 __attribute__((ext_vector_type(8)));
typedef float f32x4 __attribute__((ext_vector_type(4)));

// ws layout (bytes):
//  [0, 33554432)        W' = bf16(w), row-major [16][1024][1024]
//  [33554432, 50331648) X' = bf16(x), S-MAJOR [s:128][b:64][d:1024]
//  [50331648]           npairs (int, 16-byte slot)
//  [50331664, +72*16)   pairs int4 {s0, s1, layer, 0}
#define WS_W     0ull
#define WS_X     33554432ull
#define WS_P     50331648ull
#define WS_PAIRS (WS_P + 16ull)
#define WS_NEED  (WS_PAIRS + 72ull * 16ull)

__device__ __forceinline__ unsigned f2bf2(float a, float b) {
    union { float f; unsigned u; } x{a}, y{b};
    unsigned lo = x.u + 0x7FFFu + ((x.u >> 16) & 1u);
    unsigned hi = y.u + 0x7FFFu + ((y.u >> 16) & 1u);
    return (lo >> 16) | (hi & 0xFFFF0000u);
}

__device__ __forceinline__ void gload16(const void* g, void* l) {
    __builtin_amdgcn_global_load_lds(
        (const __attribute__((address_space(1))) void*)g,
        (__attribute__((address_space(3))) void*)l, 16, 0, 0);
}

// ---- pass 1: linear fp32 -> bf16 cast (R14, unchanged). ----
__global__ __launch_bounds__(256) void moshi_convert(
    const float* __restrict__ x, const float* __restrict__ w,
    const int* __restrict__ lidx, unsigned char* __restrict__ ws) {
    if (blockIdx.x == 0 && threadIdx.x < 16) {
        int t = threadIdx.x;
        int cnt[16];
        #pragma unroll 1
        for (int m = 0; m < 16; ++m) cnt[m] = 0;
        for (int s = 0; s < S_; ++s) ++cnt[lidx[s]];
        int off = 0;
        for (int m = 0; m < t; ++m) off += (cnt[m] + 1) >> 1;
        int4* pairs = (int4*)(ws + WS_PAIRS);
        int k = 0, prev = -1;
        for (int s = 0; s < S_; ++s) {
            if (lidx[s] == t) {
                if (k & 1) pairs[off + (k >> 1)] = make_int4(prev, s, t, 0);
                prev = s; ++k;
            }
        }
        if (k & 1) pairs[off + (k >> 1)] = make_int4(prev, prev, t, 0);
        if (t == 0) {
            int tot = 0;
            for (int m = 0; m < 16; ++m) tot += (cnt[m] + 1) >> 1;
            *(int*)(ws + WS_P) = tot;
        }
    }
    unsigned i0 = blockIdx.x * 512u + threadIdx.x;
    if (blockIdx.x < 8192) {                    // W: 4194304 float4s, linear
        const float4* src = reinterpret_cast<const float4*>(w);
        uint2* dst = reinterpret_cast<uint2*>(ws + WS_W);
        float4 v0 = src[i0];
        float4 v1 = src[i0 + 256];
        dst[i0]       = make_uint2(f2bf2(v0.x, v0.y), f2bf2(v0.z, v0.w));
        dst[i0 + 256] = make_uint2(f2bf2(v1.x, v1.y), f2bf2(v1.z, v1.w));
    } else {                                    // x: 2097152 float4s, b<->s transpose
        const float4* src = reinterpret_cast<const float4*>(x);
        uint2* dst = reinterpret_cast<uint2*>(ws + WS_X);
        unsigned j = i0 - 4194304u;
        float4 v0 = src[j];
        float4 v1 = src[j + 256];
        unsigned b0 = j >> 15, s0 = (j >> 8) & 127u, d40 = j & 255u;
        dst[(s0 * 64u + b0) * 256u + d40] =
            make_uint2(f2bf2(v0.x, v0.y), f2bf2(v0.z, v0.w));
        unsigned j1 = j + 256u;
        unsigned b1 = j1 >> 15, s1 = (j1 >> 8) & 127u, d41 = j1 & 255u;
        dst[(s1 * 64u + b1) * 256u + d41] =
            make_uint2(f2bf2(v1.x, v1.y), f2bf2(v1.z, v1.w));
    }
}

// ---- pass 2: paired GEMM with double-buffered counted-vmcnt pipeline
// (T3/T4 at 512 threads: 64 KB LDS, 2 blocks/CU = 16 waves/CU — R4's retry
// without the 8-waves/CU occupancy confound). Tile M=128 (2s x 64b) x N=128,
// BK=64, 8 waves, 64x32/wave. Per iter: ds_read(buf[cur]) -> lgkmcnt(0) ->
// barrier -> STAGE(kt+2 -> buf[cur]) -> MFMA -> vmcnt(4) (tile kt+1 done,
// kt+2's 4 loads stay in flight) -> barrier. Never drains vmcnt to 0 in loop.
__global__ __launch_bounds__(512, 4) void moshi_gemm_db(
    const unsigned char* __restrict__ ws, float* __restrict__ out) {
    __shared__ __align__(16) unsigned char buf[2][32768];  // [lw 16K | lx 16K]

    // bijective XCD-chunk swizzle: grid 576 = 8 chunks of 72 (9 pairs x 8 nt)
    const int bid = (blockIdx.x & 7) * 72 + (blockIdx.x >> 3);
    const int pi = bid >> 3;
    const int nt = bid & 7;
    const int np = *reinterpret_cast<const int*>(ws + WS_P);
    if (pi >= np) return;   // block-uniform exit before any barrier
    const int4 pr = *reinterpret_cast<const int4*>(ws + WS_PAIRS + 16ull * pi);
    const int s0 = pr.x, s1 = pr.y, l = pr.z;

    const int tid = threadIdx.x, lane = tid & 63, wid = tid >> 6;

    // staging sources (source-side XOR swizzle, R11/R14)
    const int rowq = tid >> 3;
    const int c16  = (tid & 7) << 4;
    const int csw  = c16 ^ ((rowq & 7) << 4);
    const unsigned char* wsrc0 = ws + WS_W
        + ((size_t)(l * 1024 + nt * 128 + rowq) << 11) + csw;
    const unsigned char* wsrc1 = wsrc0 + ((size_t)64 << 11);
    const unsigned char* xsrc0 = ws + WS_X + ((size_t)(s0 * 64 + rowq) << 11) + csw;
    const unsigned char* xsrc1 = ws + WS_X + ((size_t)(s1 * 64 + rowq) << 11) + csw;

    // fragment read addressing: lw at buffer offset 0, lx at 16384
    const int wm = wid >> 2, wn = wid & 3;
    const int swz = (lane & 7) << 4;
    const int kb  = (lane >> 4) << 4;
    const int a_base = 16384 + (wm * 64 + (lane & 15)) * 128 + kb;   // x rows
    const int b_base = (wn * 32 + (lane & 15)) * 128 + kb;           // W rows

    f32x4 acc[4][2];
    #pragma unroll
    for (int i = 0; i < 4; ++i)
        #pragma unroll
        for (int j = 0; j < 2; ++j) acc[i][j] = (f32x4)0.0f;

    auto STAGE = [&](int kt, int b) {
        gload16(wsrc0 + kt * 128, buf[b] + tid * 16);
        gload16(wsrc1 + kt * 128, buf[b] + tid * 16 + 8192);
        gload16(xsrc0 + kt * 128, buf[b] + 16384 + tid * 16);
        gload16(xsrc1 + kt * 128, buf[b] + 16384 + tid * 16 + 8192);
    };

    // prologue: two tiles in flight; wait only for tile 0 (4 oldest loads)
    STAGE(0, 0);
    STAGE(1, 1);
    asm volatile("s_waitcnt vmcnt(4)" ::: "memory");
    __builtin_amdgcn_s_barrier();

    int cur = 0;
    #pragma unroll 1
    for (int kt = 0; kt < 16; ++kt) {
        const unsigned char* bc = buf[cur];

        // 1) pull tile kt's fragments to registers (12 x ds_read_b128)
        bf16x8 af[2][4], bfr[2][2];
        #pragma unroll
        for (int kk = 0; kk < 2; ++kk) {
            #pragma unroll
            for (int mi = 0; mi < 4; ++mi)
                af[kk][mi] = *reinterpret_cast<const bf16x8*>(
                    bc + (((a_base + kk * 64) ^ swz) + mi * 2048));
            #pragma unroll
            for (int ni = 0; ni < 2; ++ni)
                bfr[kk][ni] = *reinterpret_cast<const bf16x8*>(
                    bc + (((b_base + kk * 64) ^ swz) + ni * 2048));
        }
        asm volatile("s_waitcnt lgkmcnt(0)" ::: "memory");
        __builtin_amdgcn_sched_barrier(0);     // rule #18: MFMA must not hoist
        __builtin_amdgcn_s_barrier();          // all waves done reading buf[cur]

        // 2) overwrite buf[cur] with tile kt+2 (loads fly across MFMA + next phase)
        if (kt + 2 < 16) STAGE(kt + 2, cur);
        __builtin_amdgcn_sched_barrier(0);

        // 3) MFMA cluster
        __builtin_amdgcn_s_setprio(1);
        #pragma unroll
        for (int kk = 0; kk < 2; ++kk)
            #pragma unroll
            for (int mi = 0; mi < 4; ++mi)
                #pragma unroll
                for (int ni = 0; ni < 2; ++ni)
                    acc[mi][ni] = __builtin_amdgcn_mfma_f32_16x16x32_bf16(
                        af[kk][mi], bfr[kk][ni], acc[mi][ni], 0, 0, 0);
        __builtin_amdgcn_s_setprio(0);

        if (kt == 15) break;
        // 4) counted wait: tile kt+1's 4 loads done; kt+2's stay in flight
        if (kt + 2 < 16) asm volatile("s_waitcnt vmcnt(4)" ::: "memory");
        else             asm volatile("s_waitcnt vmcnt(0)" ::: "memory");
        __builtin_amdgcn_s_barrier();          // buf[cur^1] = tile kt+1 ready
        cur ^= 1;
    }

    // epilogue: C/D col = lane&15 (o), row = (lane>>4)*4 + reg (b)
    const int s_sel = wm ? s1 : s0;
    const int col0 = nt * 128 + wn * 32 + (lane & 15);
    const int r0 = (lane >> 4) << 2;
    #pragma unroll
    for (int mi = 0; mi < 4; ++mi)
        #pragma unroll
        for (int ni = 0; ni < 2; ++ni)
            #pragma unroll
            for (int r = 0; r < 4; ++r) {
                int b = mi * 16 + r0 + r;
                out[((size_t)b * S_ + s_sel) * O_ + col0 + ni * 16] = acc[mi][ni][r];
            }
}

// ---- fallback (round-1 kernel) if ws is too small ----
__global__ __launch_bounds__(256) void moshi_flin_fallback(
    const float* __restrict__ x, const int* __restrict__ lidx,
    const float* __restrict__ w, float* __restrict__ out) {
    __shared__ __align__(16) unsigned char lxs[64 * 128];
    __shared__ __align__(16) unsigned char lws[128 * 128];
    const int bid = blockIdx.x;
    const int s = bid >> 3, n0 = (bid & 7) << 7;
    const int tid = threadIdx.x, lane = tid & 63, wid = tid >> 6;
    const int idx = lidx[s];
    const float* wb = w + (size_t)idx * O_ * D_ + (size_t)n0 * D_;
    const float* xb = x + (size_t)s * D_;
    const int swz = (lane & 7) << 4;
    const int kb = (lane >> 4) << 4;
    const int a_base = (lane & 15) * 128 + kb;
    const int b_base = (wid * 32 + (lane & 15)) * 128 + kb;
    f32x4 acc[4][2];
    #pragma unroll
    for (int i = 0; i < 4; ++i)
        #pragma unroll
        for (int j = 0; j < 2; ++j) acc[i][j] = (f32x4)0.0f;
    for (int kt = 0; kt < D_; kt += 64) {
        __syncthreads();
        #pragma unroll
        for (int p = 0; p < 4; ++p) {
            int f = tid + p * 256, row = f >> 4, cc = (f & 15) << 2;
            const float4 v = *reinterpret_cast<const float4*>(
                xb + (size_t)row * (S_ * D_) + kt + cc);
            uint2 pk = { f2bf2(v.x, v.y), f2bf2(v.z, v.w) };
            *reinterpret_cast<uint2*>(&lxs[(row * 128 + cc * 2) ^ ((row & 7) << 4)]) = pk;
        }
        #pragma unroll
        for (int p = 0; p < 8; ++p) {
            int f = tid + p * 256, row = f >> 4, cc = (f & 15) << 2;
            const float4 v = *reinterpret_cast<const float4*>(
                wb + (size_t)row * D_ + kt + cc);
            uint2 pk = { f2bf2(v.x, v.y), f2bf2(v.z, v.w) };
            *reinterpret_cast<uint2*>(&lws[(row * 128 + cc * 2) ^ ((row & 7) << 4)]) = pk;
        }
        __syncthreads();
        #pragma unroll
        for (int kk = 0; kk < 2; ++kk) {
            bf16x8 af[4], bfr[2];
            #pragma unroll
            for (int mi = 0; mi < 4; ++mi)
                af[mi] = *reinterpret_cast<const bf16x8*>(
                    &lxs[(((a_base + kk * 64) ^ swz) + mi * 2048)]);
            #pragma unroll
            for (int ni = 0; ni < 2; ++ni)
                bfr[ni] = *reinterpret_cast<const bf16x8*>(
                    &lws[(((b_base + kk * 64) ^ swz) + ni * 2048)]);
            #pragma unroll
            for (int mi = 0; mi < 4; ++mi)
                #pragma unroll
                for (int ni = 0; ni < 2; ++ni)
                    acc[mi][ni] = __builtin_amdgcn_mfma_f32_16x16x32_bf16(
                        af[mi], bfr[ni], acc[mi][ni], 0, 0, 0);
        }
    }
    float* ob = out + (size_t)s * O_ + n0 + wid * 32 + (lane & 15);
    const int r0 = (lane >> 4) << 2;
    #pragma unroll
    for (int mi = 0; mi < 4; ++mi)
        #pragma unroll
        for (int ni = 0; ni < 2; ++ni)
            #pragma unroll
            for (int r = 0; r < 4; ++r) {
                int b = mi * 16 + r0 + r;
                ob[(size_t)b * (S_ * O_) + ni * 16] = acc[mi][ni][r];
            }
}

extern "C" void kernel_launch(void* const* d_in, const int* in_sizes, int n_in,
                              void* d_out, int out_size, void* d_ws, size_t ws_size,
                              hipStream_t stream) {
    const float* x  = (const float*)d_in[0];
    const int* lidx = (const int*)d_in[1];
    const float* w  = (const float*)d_in[2];
    float* out      = (float*)d_out;

    if (ws_size < WS_NEED) {
        moshi_flin_fallback<<<dim3(128 * 8), dim3(256), 0, stream>>>(x, lidx, w, out);
        return;
    }
    unsigned char* ws = (unsigned char*)d_ws;
    moshi_convert<<<dim3(12288), dim3(256), 0, stream>>>(x, w, lidx, ws);
    moshi_gemm_db<<<dim3(72 * 8), dim3(512), 0, stream>>>(ws, out);
}